// Round 10
// baseline (62.673 us; speedup 1.0000x reference)
//
#include <hip/hip_runtime.h>
#include <math.h>

constexpr int cB = 8, cN = 1600, cT = 64, cH = 32, cHEADS = 4, cHOR = 12;
constexpr int cROWS = cB * cN; // 12800

typedef __attribute__((ext_vector_type(8))) short short8;
typedef __attribute__((ext_vector_type(4))) float f32x4;

__device__ __forceinline__ float sigmoidf_(float x) { return 1.0f / (1.0f + __expf(-x)); }
__device__ __forceinline__ float tanhf_(float x) {
    float xc = fminf(fmaxf(x, -15.0f), 15.0f);
    float e = __expf(-2.0f * xc);
    return (1.0f - e) / (1.0f + e);
}
__device__ __forceinline__ float elu1_(float x) { return (x > 0.0f) ? (x + 1.0f) : __expf(x); }
__device__ __forceinline__ short f2bf(float f) {   // RNE fp32->bf16
    unsigned u = __float_as_uint(f);
    u = (u + 0x7fffu + ((u >> 16) & 1u)) >> 16;
    return (short)u;
}

// kA: conv/BN/ReLU -> MFMA feat GEMM (inline fp32->bf16 weights, K split over 4 waves)
// -> qkv via in-block effective Wq (LDS-staged) -> z folded into qe -> kv partial.
// 16 rows/block, 800 blocks x 256 threads.
__global__ __launch_bounds__(256, 2) void kA(
    const float* __restrict__ x,
    const float* __restrict__ dw_w, const float* __restrict__ dw_b,
    const float* __restrict__ bn1_g, const float* __restrict__ bn1_b,
    const float* __restrict__ bn1_m, const float* __restrict__ bn1_v,
    const float* __restrict__ pw_w, const float* __restrict__ pw_b,
    const float* __restrict__ bn2_g, const float* __restrict__ bn2_b,
    const float* __restrict__ bn2_m, const float* __restrict__ bn2_v,
    const float* __restrict__ fp_w, const float* __restrict__ fp_b,
    const float* __restrict__ lo_w, const float* __restrict__ lo_b,
    const float* __restrict__ hi_w, const float* __restrict__ hi_b,
    float* __restrict__ feat_c, float* __restrict__ qe,
    float* __restrict__ pkv)
{
    __shared__ float y1s[16 * 65];    // 1040
    __shared__ float pacc[4][512];    // 2048
    __shared__ float sWq[96 * 33];    // 3168
    __shared__ float sbq[96];
    __shared__ float sfeat[16 * 36];  // 576
    __shared__ float ske[16 * 33];    // 528
    __shared__ float svv[16 * 33];    // 528

    const int tid = threadIdx.x;
    const int l = tid & 63;
    const int w = __builtin_amdgcn_readfirstlane(tid >> 6); // 0..3 = K-slice
    const int bk = blockIdx.x;
    const int r0 = bk * 16;
    const int b = r0 / cN;          // uniform (16 | 1600)
    const int n0 = r0 - b * cN;

    // ---- P0a: y1 conv ----
    {
        const float inv1 = bn1_g[0] * rsqrtf(bn1_v[0] + 1e-5f);
        const float A = inv1;
        const float C = (dw_b[0] - bn1_m[0]) * inv1 + bn1_b[0];
        const float w0 = dw_w[0], w1 = dw_w[1], w2 = dw_w[2];
        const int rr = tid & 15;
        const int t0 = (tid >> 4) * 4;
        const float* xp = x + (size_t)b * cT * cN + (n0 + rr);
        float xv[6];
        #pragma unroll
        for (int q = 0; q < 6; ++q) {
            const int t = t0 - 1 + q;
            xv[q] = (t >= 0 && t < cT) ? xp[(size_t)t * cN] : 0.0f;
        }
        #pragma unroll
        for (int q = 0; q < 4; ++q) {
            const float s = w0 * xv[q] + w1 * xv[q + 1] + w2 * xv[q + 2];
            y1s[rr * 65 + t0 + q] = fmaxf(0.0f, fmaf(s, A, C));
        }
    }
    // ---- P0b: build effective Wq = hi_w @ lo_w (+ bias) in LDS ----
    #pragma unroll
    for (int k = 0; k < 12; ++k) {
        const int g = tid + k * 256;          // 0..3071
        const int oi = g >> 5, i = g & 31;
        float s = 0.0f;
        #pragma unroll
        for (int p = 0; p < 24; ++p) s = fmaf(hi_w[oi * 24 + p], lo_w[p * 32 + i], s);
        sWq[oi * 33 + i] = s;
    }
    if (tid < 96) {
        float s = hi_b[tid];
        #pragma unroll
        for (int p = 0; p < 24; ++p) s = fmaf(hi_w[tid * 24 + p], lo_b[p], s);
        sbq[tid] = s;
    }
    __syncthreads();

    // ---- P1: MFMA feat GEMM, wave w = K-slice, inline fp32->bf16 B fragments ----
    {
        float a2r[4], c2r[4];
        #pragma unroll
        for (int cc = 0; cc < 4; ++cc) {
            const int c = w * 4 + cc;
            const float inv2 = bn2_g[c] * rsqrtf(bn2_v[c] + 1e-5f);
            a2r[cc] = pw_w[c] * inv2;
            c2r[cc] = (pw_b[c] - bn2_m[c]) * inv2 + bn2_b[c];
        }
        const int rl = l & 15;
        const int off = (l >> 4) * 8;
        float y1r[16];
        #pragma unroll
        for (int p = 0; p < 8; ++p) {
            y1r[p]     = y1s[rl * 65 + off + p];
            y1r[8 + p] = y1s[rl * 65 + 32 + off + p];
        }
        const float* f0p = fp_w + (size_t)(l & 15) * 1024 + off;
        const float* f1p = fp_w + (size_t)(16 + (l & 15)) * 1024 + off;

        f32x4 acc0 = {0.f, 0.f, 0.f, 0.f};
        f32x4 acc1 = {0.f, 0.f, 0.f, 0.f};

        #pragma unroll
        for (int q = 0; q < 8; ++q) {
            const int kk = w * 8 + q;               // uniform
            const float a2 = a2r[q >> 1], c2v = c2r[q >> 1];
            short8 af, bf0, bf1;
            #pragma unroll
            for (int i = 0; i < 8; ++i) {
                const float y2 = fmaxf(0.0f, fmaf(a2, y1r[(q & 1) * 8 + i], c2v));
                af[i] = f2bf(y2);
            }
            {
                const float4 va = *(const float4*)(f0p + kk * 32);
                const float4 vb = *(const float4*)(f0p + kk * 32 + 4);
                bf0[0] = f2bf(va.x); bf0[1] = f2bf(va.y); bf0[2] = f2bf(va.z); bf0[3] = f2bf(va.w);
                bf0[4] = f2bf(vb.x); bf0[5] = f2bf(vb.y); bf0[6] = f2bf(vb.z); bf0[7] = f2bf(vb.w);
            }
            {
                const float4 va = *(const float4*)(f1p + kk * 32);
                const float4 vb = *(const float4*)(f1p + kk * 32 + 4);
                bf1[0] = f2bf(va.x); bf1[1] = f2bf(va.y); bf1[2] = f2bf(va.z); bf1[3] = f2bf(va.w);
                bf1[4] = f2bf(vb.x); bf1[5] = f2bf(vb.y); bf1[6] = f2bf(vb.z); bf1[7] = f2bf(vb.w);
            }
            acc0 = __builtin_amdgcn_mfma_f32_16x16x32_bf16(af, bf0, acc0, 0, 0, 0);
            acc1 = __builtin_amdgcn_mfma_f32_16x16x32_bf16(af, bf1, acc1, 0, 0, 0);
        }

        // partials: C/D layout col=l&15, row=(l>>4)*4+reg
        const int col = l & 15;
        const int rb = (l >> 4) * 4;
        #pragma unroll
        for (int reg = 0; reg < 4; ++reg) {
            pacc[w][(rb + reg) * 32 + col]      = acc0[reg];
            pacc[w][(rb + reg) * 32 + 16 + col] = acc1[reg];
        }
    }
    __syncthreads();

    // ---- P2: reduce partials + fp_b -> sfeat + feat_c ----
    #pragma unroll
    for (int o2 = 0; o2 < 2; ++o2) {
        const int o = tid + o2 * 256;          // 0..511 = rp*32+h
        const int rp = o >> 5, h = o & 31;
        const float s = pacc[0][o] + pacc[1][o] + pacc[2][o] + pacc[3][o] + fp_b[h];
        sfeat[rp * 36 + h] = s;
        feat_c[(size_t)r0 * cH + o] = s;       // coalesced
    }
    __syncthreads();

    // ---- P3: qkv, 16 lanes/row; outputs {j, j+16} of q,k,v ----
    const int r = tid >> 4;
    const int j = tid & 15;
    float q0, q1;
    {
        float s0 = sbq[j],      s1 = sbq[16 + j];
        float s2 = sbq[32 + j], s3 = sbq[48 + j];
        float s4 = sbq[64 + j], s5 = sbq[80 + j];
        #pragma unroll
        for (int i = 0; i < cH; ++i) {
            const float fv = sfeat[r * 36 + i];          // broadcast
            s0 = fmaf(fv, sWq[(j) * 33 + i], s0);
            s1 = fmaf(fv, sWq[(16 + j) * 33 + i], s1);
            s2 = fmaf(fv, sWq[(32 + j) * 33 + i], s2);
            s3 = fmaf(fv, sWq[(48 + j) * 33 + i], s3);
            s4 = fmaf(fv, sWq[(64 + j) * 33 + i], s4);
            s5 = fmaf(fv, sWq[(80 + j) * 33 + i], s5);
        }
        q0 = elu1_(s0); q1 = elu1_(s1);
        ske[r * 33 + j]      = elu1_(s2);
        ske[r * 33 + 16 + j] = elu1_(s3);
        svv[r * 33 + j]      = s4;
        svv[r * 33 + 16 + j] = s5;
    }
    __syncthreads();

    // ---- P4: z-fold into qe ----
    {
        const int h0 = j >> 3, h1 = 2 + (j >> 3);
        float zs0 = 1e-8f, zs1 = 1e-8f;
        #pragma unroll
        for (int d = 0; d < 8; ++d) {
            zs0 += ske[r * 33 + h0 * 8 + d];
            zs1 += ske[r * 33 + h1 * 8 + d];
        }
        const int row = r0 + r;
        qe[(size_t)row * cH + j]      = q0 / zs0;
        qe[(size_t)row * cH + 16 + j] = q1 / zs1;
    }

    // ---- P5: kv partial over 16 rows -> pkv ----
    {
        const int h = tid >> 6, d = (tid >> 3) & 7, e = tid & 7;
        float s = 0.0f;
        #pragma unroll
        for (int rr3 = 0; rr3 < 16; ++rr3)
            s = fmaf(ske[rr3 * 33 + h * 8 + d], svv[rr3 * 33 + h * 8 + e], s);
        pkv[(size_t)bk * 256 + tid] = s;
    }
}

// kB: in-block Wo build + pkv reduce (100 partials) + att + out-proj + GRU + blend.
// 32 rows/block, 400 blocks x 256 threads.
__global__ __launch_bounds__(256) void kB(
    const float* __restrict__ x,
    const float* __restrict__ feat_c, const float* __restrict__ qe,
    const float* __restrict__ pkv,
    const float* __restrict__ olo_w, const float* __restrict__ olo_b,
    const float* __restrict__ ohi_w, const float* __restrict__ ohi_b,
    const float* __restrict__ hp_w, const float* __restrict__ hp_b,
    const float* __restrict__ gru_wih, const float* __restrict__ gru_whh,
    const float* __restrict__ gru_bih, const float* __restrict__ gru_bhh,
    const float* __restrict__ op_w, const float* __restrict__ op_b,
    const float* __restrict__ log_decay,
    const float* __restrict__ rg1_w, const float* __restrict__ rg1_b,
    const float* __restrict__ rg2_w, const float* __restrict__ rg2_b,
    const float* __restrict__ log_reg,
    float* __restrict__ out)
{
    __shared__ float sA[32][36];
    __shared__ float sB[32][36];
    __shared__ float sC[32][36];
    __shared__ float skv[256];
    __shared__ float sWo[32 * 33];
    __shared__ float sbo[32];

    const int tid = threadIdx.x;
    const int r = tid >> 3;
    const int j = tid & 7;
    const int row = blockIdx.x * 32 + r;
    const int b = __builtin_amdgcn_readfirstlane((blockIdx.x * 32) / cN);
    const int n = row - b * cN;

    // effective Wo = ohi_w @ olo_w (+ bias)
    #pragma unroll
    for (int k = 0; k < 4; ++k) {
        const int g = tid + k * 256;          // 0..1023
        const int oi = g >> 5, i = g & 31;
        float s = 0.0f;
        #pragma unroll
        for (int p = 0; p < 8; ++p) s = fmaf(ohi_w[oi * 8 + p], olo_w[p * 32 + i], s);
        sWo[oi * 33 + i] = s;
    }
    if (tid < 32) {
        float s = ohi_b[tid];
        #pragma unroll
        for (int p = 0; p < 8; ++p) s = fmaf(ohi_w[tid * 8 + p], olo_b[p], s);
        sbo[tid] = s;
    }

    // kv reduction: thread = combo, 100 partials of this batch
    {
        const float* pp = pkv + (size_t)(b * 100) * 256 + tid;
        float s0 = 0.f, s1 = 0.f, s2 = 0.f, s3 = 0.f;
        #pragma unroll 4
        for (int p = 0; p < 100; p += 4) {
            s0 += pp[(size_t)(p + 0) * 256];
            s1 += pp[(size_t)(p + 1) * 256];
            s2 += pp[(size_t)(p + 2) * 256];
            s3 += pp[(size_t)(p + 3) * 256];
        }
        skv[tid] = (s0 + s1) + (s2 + s3);
    }

    {
        const float4* q4 = (const float4*)(qe + (size_t)row * cH);
        float4 v = q4[j];
        *(float4*)&sA[r][4 * j] = v;
    }
    __syncthreads();

    float o_m[4];
    #pragma unroll
    for (int m = 0; m < 4; ++m) {
        float s = 0.0f;
        #pragma unroll
        for (int d = 0; d < 8; ++d)
            s = fmaf(sA[r][m * 8 + d], skv[m * 64 + d * 8 + j], s);
        o_m[m] = s;
    }
    #pragma unroll
    for (int m = 0; m < 4; ++m) sB[r][m * 8 + j] = o_m[m];
    __syncthreads();

    float f2_m[4];
    #pragma unroll
    for (int m = 0; m < 4; ++m) {
        const int i = m * 8 + j;
        float s = sbo[i];
        #pragma unroll
        for (int q = 0; q < 32; ++q) s = fmaf(sB[r][q], sWo[i * 33 + q], s);
        f2_m[m] = feat_c[(size_t)row * cH + i] + s;
        sC[r][i] = f2_m[m];
    }
    __syncthreads();

    float h0_j = hp_b[j], g1_j = rg1_b[j];
    #pragma unroll
    for (int i = 0; i < cH; ++i) {
        const float fv = sC[r][i];
        h0_j = fmaf(fv, hp_w[j * cH + i], h0_j);
        g1_j = fmaf(fv, rg1_w[j * cH + i], g1_j);
    }
    g1_j = fmaxf(0.0f, g1_j);

    float g1f[8];
    #pragma unroll
    for (int i = 0; i < 8; ++i) g1f[i] = __shfl(g1_j, i, 8);

    float ga = rg2_b[j], gb_ = rg2_b[8 + (j & 3)];
    #pragma unroll
    for (int q = 0; q < 8; ++q) {
        ga = fmaf(g1f[q], rg2_w[j * 8 + q], ga);
        gb_ = fmaf(g1f[q], rg2_w[(8 + (j & 3)) * 8 + q], gb_);
    }
    const float gate_a = sigmoidf_(ga);
    const float gate_b = sigmoidf_(gb_);

    const float last = x[(size_t)b * cT * cN + (size_t)(cT - 1) * cN + n];

    float whh_r[8], whh_z[8], whh_n[8], opw[8];
    #pragma unroll
    for (int i = 0; i < 8; ++i) {
        whh_r[i] = gru_whh[j * 8 + i];
        whh_z[i] = gru_whh[(8 + j) * 8 + i];
        whh_n[i] = gru_whh[(16 + j) * 8 + i];
        opw[i] = op_w[i];
    }
    const float wih_r = gru_wih[j], wih_z = gru_wih[8 + j], wih_n = gru_wih[16 + j];
    const float bih_r = gru_bih[j], bih_z = gru_bih[8 + j], bih_n = gru_bih[16 + j];
    const float bhh_r = gru_bhh[j], bhh_z = gru_bhh[8 + j], bhh_n = gru_bhh[16 + j];
    const float opb = op_b[0];

    float h_full[8];
    #pragma unroll
    for (int i = 0; i < 8; ++i) h_full[i] = __shfl(h0_j, i, 8);
    float h_own = h0_j;
    float cur = last;
    float po_a = 0.0f, po_b = 0.0f;

    #pragma unroll
    for (int s = 0; s < cHOR; ++s) {
        float ghr = bhh_r, ghz = bhh_z, ghn = bhh_n;
        #pragma unroll
        for (int i = 0; i < 8; ++i) {
            ghr = fmaf(h_full[i], whh_r[i], ghr);
            ghz = fmaf(h_full[i], whh_z[i], ghz);
            ghn = fmaf(h_full[i], whh_n[i], ghn);
        }
        const float r_ = sigmoidf_(fmaf(wih_r, cur, bih_r) + ghr);
        const float zg = sigmoidf_(fmaf(wih_z, cur, bih_z) + ghz);
        const float nn = tanhf_(fmaf(wih_n, cur, bih_n) + r_ * ghn);
        const float hn = (1.0f - zg) * nn + zg * h_own;
        h_own = hn;
        #pragma unroll
        for (int i = 0; i < 8; ++i) h_full[i] = __shfl(hn, i, 8);
        float p = opb;
        #pragma unroll
        for (int i = 0; i < 8; ++i) p = fmaf(h_full[i], opw[i], p);
        po_a = (s == j) ? p : po_a;
        po_b = (s == 8 + j) ? p : po_b;
        cur = p;
    }

    const float dk = __expf(log_decay[0]);
    float* orow = out + (size_t)row * 12;
    orow[j] = gate_a * po_a + (1.0f - gate_a) * last * __expf(-dk * (float)(j + 1));
    if (j < 4)
        orow[8 + j] = gate_b * po_b + (1.0f - gate_b) * last * __expf(-dk * (float)(j + 9));

    if (row == 0 && j == 0)
        out[(size_t)cROWS * 12] = __expf(log_reg[0]) * (1.0f / (float)cN);
}

extern "C" void kernel_launch(void* const* d_in, const int* in_sizes, int n_in,
                              void* d_out, int out_size, void* d_ws, size_t ws_size,
                              hipStream_t stream)
{
    const float* x      = (const float*)d_in[0];
    const float* dw_w   = (const float*)d_in[1];
    const float* dw_b   = (const float*)d_in[2];
    const float* bn1_g  = (const float*)d_in[3];
    const float* bn1_b  = (const float*)d_in[4];
    const float* bn1_m  = (const float*)d_in[5];
    const float* bn1_v  = (const float*)d_in[6];
    const float* pw_w   = (const float*)d_in[7];
    const float* pw_b   = (const float*)d_in[8];
    const float* bn2_g  = (const float*)d_in[9];
    const float* bn2_b  = (const float*)d_in[10];
    const float* bn2_m  = (const float*)d_in[11];
    const float* bn2_v  = (const float*)d_in[12];
    const float* fp_w   = (const float*)d_in[13];
    const float* fp_b   = (const float*)d_in[14];
    const float* lo_w   = (const float*)d_in[15];
    const float* lo_b   = (const float*)d_in[16];
    const float* hi_w   = (const float*)d_in[17];
    const float* hi_b   = (const float*)d_in[18];
    const float* olo_w  = (const float*)d_in[19];
    const float* olo_b  = (const float*)d_in[20];
    const float* ohi_w  = (const float*)d_in[21];
    const float* ohi_b  = (const float*)d_in[22];
    // d_in[23]=u, d_in[24]=v dead (softmax row-sums == 1 -> mean|attn| == 1/N)
    const float* log_reg = (const float*)d_in[25];
    const float* hp_w   = (const float*)d_in[26];
    const float* hp_b   = (const float*)d_in[27];
    const float* gru_wih = (const float*)d_in[28];
    const float* gru_whh = (const float*)d_in[29];
    const float* gru_bih = (const float*)d_in[30];
    const float* gru_bhh = (const float*)d_in[31];
    const float* op_w   = (const float*)d_in[32];
    const float* op_b   = (const float*)d_in[33];
    const float* log_decay = (const float*)d_in[34];
    const float* rg1_w  = (const float*)d_in[35];
    const float* rg1_b  = (const float*)d_in[36];
    const float* rg2_w  = (const float*)d_in[37];
    const float* rg2_b  = (const float*)d_in[38];

    float* ws = (float*)d_ws;
    float* qe     = ws;                            // 409600 (z pre-folded)
    float* feat_c = qe + 409600;                   // 409600
    float* pkv    = feat_c + 409600;               // 204800 [800][256]

    kA<<<800, 256, 0, stream>>>(x, dw_w, dw_b, bn1_g, bn1_b, bn1_m, bn1_v,
                                pw_w, pw_b, bn2_g, bn2_b, bn2_m, bn2_v,
                                fp_w, fp_b, lo_w, lo_b, hi_w, hi_b,
                                feat_c, qe, pkv);
    kB<<<400, 256, 0, stream>>>(x, feat_c, qe, pkv,
                                olo_w, olo_b, ohi_w, ohi_b,
                                hp_w, hp_b, gru_wih, gru_whh, gru_bih, gru_bhh,
                                op_w, op_b, log_decay,
                                rg1_w, rg1_b, rg2_w, rg2_b, log_reg,
                                (float*)d_out);
}

// Round 11
// 42.333 us; speedup vs baseline: 1.4805x; 1.4805x over previous
//
#include <hip/hip_runtime.h>
#include <math.h>

constexpr int cB = 8, cN = 1600, cT = 64, cH = 32, cHEADS = 4, cHOR = 12;
constexpr int cROWS = cB * cN; // 12800

typedef __attribute__((ext_vector_type(8))) short short8;
typedef __attribute__((ext_vector_type(4))) float f32x4;

__device__ __forceinline__ float sigmoidf_(float x) { return 1.0f / (1.0f + __expf(-x)); }
__device__ __forceinline__ float tanhf_(float x) {
    float xc = fminf(fmaxf(x, -15.0f), 15.0f);
    float e = __expf(-2.0f * xc);
    return (1.0f - e) / (1.0f + e);
}
__device__ __forceinline__ float elu1_(float x) { return (x > 0.0f) ? (x + 1.0f) : __expf(x); }
__device__ __forceinline__ short f2bf(float f) {   // RNE fp32->bf16
    unsigned u = __float_as_uint(f);
    u = (u + 0x7fffu + ((u >> 16) & 1u)) >> 16;
    return (short)u;
}

// k0_prep: wbt = bf16(fp_w); W_qkv_eff = hi_w@lo_w (+bias).
__global__ __launch_bounds__(256) void k0_prep(
    const float* __restrict__ fp_w,
    const float* __restrict__ lo_w, const float* __restrict__ lo_b,
    const float* __restrict__ hi_w, const float* __restrict__ hi_b,
    unsigned short* __restrict__ wbt,
    float* __restrict__ Wq, float* __restrict__ bq)
{
    const int g = blockIdx.x * 256 + threadIdx.x;   // 0..32767
    wbt[g] = (unsigned short)f2bf(fp_w[g]);
    if (g < 3072) {          // W_qkv_eff[96][32]
        const int oi = g >> 5, i = g & 31;
        float s = 0.0f;
        #pragma unroll
        for (int p = 0; p < 24; ++p) s = fmaf(hi_w[oi * 24 + p], lo_w[p * 32 + i], s);
        Wq[g] = s;
    }
    if (g < 96) {
        float s = hi_b[g];
        #pragma unroll
        for (int p = 0; p < 24; ++p) s = fmaf(hi_w[g * 24 + p], lo_b[p], s);
        bq[g] = s;
    }
}

// kFQ: conv/BN/ReLU -> MFMA feat GEMM (bf16 wbt, K split over 4 waves, B preloaded
// to registers) -> qkv via LDS-staged Wq -> z folded into qe -> kv partial.
// 16 rows/block, 800 blocks x 256 threads.
__global__ __launch_bounds__(256, 2) void kFQ(
    const float* __restrict__ x,
    const float* __restrict__ dw_w, const float* __restrict__ dw_b,
    const float* __restrict__ bn1_g, const float* __restrict__ bn1_b,
    const float* __restrict__ bn1_m, const float* __restrict__ bn1_v,
    const float* __restrict__ pw_w, const float* __restrict__ pw_b,
    const float* __restrict__ bn2_g, const float* __restrict__ bn2_b,
    const float* __restrict__ bn2_m, const float* __restrict__ bn2_v,
    const unsigned short* __restrict__ wbt, const float* __restrict__ fp_b,
    const float* __restrict__ Wq, const float* __restrict__ bq,
    float* __restrict__ feat_c, float* __restrict__ qe,
    float* __restrict__ pkv)
{
    __shared__ float y1s[16 * 65];    // 4160 B
    __shared__ float pacc[4][512];    // 8192 B
    __shared__ float sWq[96 * 33];    // 12672 B
    __shared__ float sbq[96];
    __shared__ float sfeat[16 * 36];  // 2304 B
    __shared__ float ske[16 * 33];    // 2112 B
    __shared__ float svv[16 * 33];    // 2112 B

    const int tid = threadIdx.x;
    const int l = tid & 63;
    const int w = __builtin_amdgcn_readfirstlane(tid >> 6); // 0..3 = K-slice
    const int bk = blockIdx.x;
    const int r0 = bk * 16;
    const int b = r0 / cN;          // uniform (16 | 1600)
    const int n0 = r0 - b * cN;

    // ---- preload B fragments for this wave's K-slice (explicit, hoisted) ----
    const int off = (l >> 4) * 8;
    const unsigned short* b0p = wbt + (size_t)(l & 15) * 1024 + off;
    const unsigned short* b1p = wbt + (size_t)(16 + (l & 15)) * 1024 + off;
    short8 b0f[8], b1f[8];
    #pragma unroll
    for (int q = 0; q < 8; ++q) {
        b0f[q] = *(const short8*)(b0p + (w * 8 + q) * 32);
        b1f[q] = *(const short8*)(b1p + (w * 8 + q) * 32);
    }

    // ---- P0a: y1 conv ----
    {
        const float inv1 = bn1_g[0] * rsqrtf(bn1_v[0] + 1e-5f);
        const float A = inv1;
        const float C = (dw_b[0] - bn1_m[0]) * inv1 + bn1_b[0];
        const float w0 = dw_w[0], w1 = dw_w[1], w2 = dw_w[2];
        const int rr = tid & 15;
        const int t0 = (tid >> 4) * 4;
        const float* xp = x + (size_t)b * cT * cN + (n0 + rr);
        float xv[6];
        #pragma unroll
        for (int q = 0; q < 6; ++q) {
            const int t = t0 - 1 + q;
            xv[q] = (t >= 0 && t < cT) ? xp[(size_t)t * cN] : 0.0f;
        }
        #pragma unroll
        for (int q = 0; q < 4; ++q) {
            const float s = w0 * xv[q] + w1 * xv[q + 1] + w2 * xv[q + 2];
            y1s[rr * 65 + t0 + q] = fmaxf(0.0f, fmaf(s, A, C));
        }
    }
    // ---- P0b: stage Wq/bq to LDS (coalesced) ----
    #pragma unroll
    for (int i = 0; i < 12; ++i) {
        const int g = tid + i * 256;          // 0..3071
        sWq[(g >> 5) * 33 + (g & 31)] = Wq[g];
    }
    if (tid < 96) sbq[tid] = bq[tid];
    __syncthreads();

    // ---- P1: MFMA feat GEMM, wave w = K-slice ----
    {
        float a2r[4], c2r[4];
        #pragma unroll
        for (int cc = 0; cc < 4; ++cc) {
            const int c = w * 4 + cc;
            const float inv2 = bn2_g[c] * rsqrtf(bn2_v[c] + 1e-5f);
            a2r[cc] = pw_w[c] * inv2;
            c2r[cc] = (pw_b[c] - bn2_m[c]) * inv2 + bn2_b[c];
        }
        const int rl = l & 15;
        float y1r[16];
        #pragma unroll
        for (int p = 0; p < 8; ++p) {
            y1r[p]     = y1s[rl * 65 + off + p];
            y1r[8 + p] = y1s[rl * 65 + 32 + off + p];
        }

        f32x4 acc0 = {0.f, 0.f, 0.f, 0.f};
        f32x4 acc1 = {0.f, 0.f, 0.f, 0.f};
        #pragma unroll
        for (int q = 0; q < 8; ++q) {
            const float a2 = a2r[q >> 1], c2v = c2r[q >> 1];
            short8 af;
            #pragma unroll
            for (int i = 0; i < 8; ++i) {
                const float y2 = fmaxf(0.0f, fmaf(a2, y1r[(q & 1) * 8 + i], c2v));
                af[i] = f2bf(y2);
            }
            acc0 = __builtin_amdgcn_mfma_f32_16x16x32_bf16(af, b0f[q], acc0, 0, 0, 0);
            acc1 = __builtin_amdgcn_mfma_f32_16x16x32_bf16(af, b1f[q], acc1, 0, 0, 0);
        }

        // partials: C/D layout col=l&15, row=(l>>4)*4+reg
        const int col = l & 15;
        const int rb = (l >> 4) * 4;
        #pragma unroll
        for (int reg = 0; reg < 4; ++reg) {
            pacc[w][(rb + reg) * 32 + col]      = acc0[reg];
            pacc[w][(rb + reg) * 32 + 16 + col] = acc1[reg];
        }
    }
    __syncthreads();

    // ---- P2: reduce partials + fp_b -> sfeat + feat_c ----
    #pragma unroll
    for (int o2 = 0; o2 < 2; ++o2) {
        const int o = tid + o2 * 256;          // 0..511 = rp*32+h
        const int rp = o >> 5, h = o & 31;
        const float s = pacc[0][o] + pacc[1][o] + pacc[2][o] + pacc[3][o] + fp_b[h];
        sfeat[rp * 36 + h] = s;
        feat_c[(size_t)r0 * cH + o] = s;       // coalesced
    }
    __syncthreads();

    // ---- P3: qkv, 16 lanes/row; outputs {j, j+16} of q,k,v ----
    const int r = tid >> 4;
    const int j = tid & 15;
    float q0, q1;
    {
        float s0 = sbq[j],      s1 = sbq[16 + j];
        float s2 = sbq[32 + j], s3 = sbq[48 + j];
        float s4 = sbq[64 + j], s5 = sbq[80 + j];
        #pragma unroll
        for (int i = 0; i < cH; ++i) {
            const float fv = sfeat[r * 36 + i];          // broadcast
            s0 = fmaf(fv, sWq[(j) * 33 + i], s0);
            s1 = fmaf(fv, sWq[(16 + j) * 33 + i], s1);
            s2 = fmaf(fv, sWq[(32 + j) * 33 + i], s2);
            s3 = fmaf(fv, sWq[(48 + j) * 33 + i], s3);
            s4 = fmaf(fv, sWq[(64 + j) * 33 + i], s4);
            s5 = fmaf(fv, sWq[(80 + j) * 33 + i], s5);
        }
        q0 = elu1_(s0); q1 = elu1_(s1);
        ske[r * 33 + j]      = elu1_(s2);
        ske[r * 33 + 16 + j] = elu1_(s3);
        svv[r * 33 + j]      = s4;
        svv[r * 33 + 16 + j] = s5;
    }
    __syncthreads();

    // ---- P4: z-fold into qe ----
    {
        const int h0 = j >> 3, h1 = 2 + (j >> 3);
        float zs0 = 1e-8f, zs1 = 1e-8f;
        #pragma unroll
        for (int d = 0; d < 8; ++d) {
            zs0 += ske[r * 33 + h0 * 8 + d];
            zs1 += ske[r * 33 + h1 * 8 + d];
        }
        const int row = r0 + r;
        qe[(size_t)row * cH + j]      = q0 / zs0;
        qe[(size_t)row * cH + 16 + j] = q1 / zs1;
    }

    // ---- P5: kv partial over 16 rows -> pkv ----
    {
        const int h = tid >> 6, d = (tid >> 3) & 7, e = tid & 7;
        float s = 0.0f;
        #pragma unroll
        for (int rr3 = 0; rr3 < 16; ++rr3)
            s = fmaf(ske[rr3 * 33 + h * 8 + d], svv[rr3 * 33 + h * 8 + e], s);
        pkv[(size_t)bk * 256 + tid] = s;
    }
}

// kB: in-block Wo build + pkv reduce (100 partials) + att + out-proj + GRU + blend.
// 32 rows/block, 400 blocks x 256 threads. (R10 version, unchanged.)
__global__ __launch_bounds__(256) void kB(
    const float* __restrict__ x,
    const float* __restrict__ feat_c, const float* __restrict__ qe,
    const float* __restrict__ pkv,
    const float* __restrict__ olo_w, const float* __restrict__ olo_b,
    const float* __restrict__ ohi_w, const float* __restrict__ ohi_b,
    const float* __restrict__ hp_w, const float* __restrict__ hp_b,
    const float* __restrict__ gru_wih, const float* __restrict__ gru_whh,
    const float* __restrict__ gru_bih, const float* __restrict__ gru_bhh,
    const float* __restrict__ op_w, const float* __restrict__ op_b,
    const float* __restrict__ log_decay,
    const float* __restrict__ rg1_w, const float* __restrict__ rg1_b,
    const float* __restrict__ rg2_w, const float* __restrict__ rg2_b,
    const float* __restrict__ log_reg,
    float* __restrict__ out)
{
    __shared__ float sA[32][36];
    __shared__ float sB[32][36];
    __shared__ float sC[32][36];
    __shared__ float skv[256];
    __shared__ float sWo[32 * 33];
    __shared__ float sbo[32];

    const int tid = threadIdx.x;
    const int r = tid >> 3;
    const int j = tid & 7;
    const int row = blockIdx.x * 32 + r;
    const int b = __builtin_amdgcn_readfirstlane((blockIdx.x * 32) / cN);
    const int n = row - b * cN;

    // effective Wo = ohi_w @ olo_w (+ bias)
    #pragma unroll
    for (int k = 0; k < 4; ++k) {
        const int g = tid + k * 256;          // 0..1023
        const int oi = g >> 5, i = g & 31;
        float s = 0.0f;
        #pragma unroll
        for (int p = 0; p < 8; ++p) s = fmaf(ohi_w[oi * 8 + p], olo_w[p * 32 + i], s);
        sWo[oi * 33 + i] = s;
    }
    if (tid < 32) {
        float s = ohi_b[tid];
        #pragma unroll
        for (int p = 0; p < 8; ++p) s = fmaf(ohi_w[tid * 8 + p], olo_b[p], s);
        sbo[tid] = s;
    }

    // kv reduction: thread = combo, 100 partials of this batch
    {
        const float* pp = pkv + (size_t)(b * 100) * 256 + tid;
        float s0 = 0.f, s1 = 0.f, s2 = 0.f, s3 = 0.f;
        #pragma unroll 4
        for (int p = 0; p < 100; p += 4) {
            s0 += pp[(size_t)(p + 0) * 256];
            s1 += pp[(size_t)(p + 1) * 256];
            s2 += pp[(size_t)(p + 2) * 256];
            s3 += pp[(size_t)(p + 3) * 256];
        }
        skv[tid] = (s0 + s1) + (s2 + s3);
    }

    {
        const float4* q4 = (const float4*)(qe + (size_t)row * cH);
        float4 v = q4[j];
        *(float4*)&sA[r][4 * j] = v;
    }
    __syncthreads();

    float o_m[4];
    #pragma unroll
    for (int m = 0; m < 4; ++m) {
        float s = 0.0f;
        #pragma unroll
        for (int d = 0; d < 8; ++d)
            s = fmaf(sA[r][m * 8 + d], skv[m * 64 + d * 8 + j], s);
        o_m[m] = s;
    }
    #pragma unroll
    for (int m = 0; m < 4; ++m) sB[r][m * 8 + j] = o_m[m];
    __syncthreads();

    float f2_m[4];
    #pragma unroll
    for (int m = 0; m < 4; ++m) {
        const int i = m * 8 + j;
        float s = sbo[i];
        #pragma unroll
        for (int q = 0; q < 32; ++q) s = fmaf(sB[r][q], sWo[i * 33 + q], s);
        f2_m[m] = feat_c[(size_t)row * cH + i] + s;
        sC[r][i] = f2_m[m];
    }
    __syncthreads();

    float h0_j = hp_b[j], g1_j = rg1_b[j];
    #pragma unroll
    for (int i = 0; i < cH; ++i) {
        const float fv = sC[r][i];
        h0_j = fmaf(fv, hp_w[j * cH + i], h0_j);
        g1_j = fmaf(fv, rg1_w[j * cH + i], g1_j);
    }
    g1_j = fmaxf(0.0f, g1_j);

    float g1f[8];
    #pragma unroll
    for (int i = 0; i < 8; ++i) g1f[i] = __shfl(g1_j, i, 8);

    float ga = rg2_b[j], gb_ = rg2_b[8 + (j & 3)];
    #pragma unroll
    for (int q = 0; q < 8; ++q) {
        ga = fmaf(g1f[q], rg2_w[j * 8 + q], ga);
        gb_ = fmaf(g1f[q], rg2_w[(8 + (j & 3)) * 8 + q], gb_);
    }
    const float gate_a = sigmoidf_(ga);
    const float gate_b = sigmoidf_(gb_);

    const float last = x[(size_t)b * cT * cN + (size_t)(cT - 1) * cN + n];

    float whh_r[8], whh_z[8], whh_n[8], opw[8];
    #pragma unroll
    for (int i = 0; i < 8; ++i) {
        whh_r[i] = gru_whh[j * 8 + i];
        whh_z[i] = gru_whh[(8 + j) * 8 + i];
        whh_n[i] = gru_whh[(16 + j) * 8 + i];
        opw[i] = op_w[i];
    }
    const float wih_r = gru_wih[j], wih_z = gru_wih[8 + j], wih_n = gru_wih[16 + j];
    const float bih_r = gru_bih[j], bih_z = gru_bih[8 + j], bih_n = gru_bih[16 + j];
    const float bhh_r = gru_bhh[j], bhh_z = gru_bhh[8 + j], bhh_n = gru_bhh[16 + j];
    const float opb = op_b[0];

    float h_full[8];
    #pragma unroll
    for (int i = 0; i < 8; ++i) h_full[i] = __shfl(h0_j, i, 8);
    float h_own = h0_j;
    float cur = last;
    float po_a = 0.0f, po_b = 0.0f;

    #pragma unroll
    for (int s = 0; s < cHOR; ++s) {
        float ghr = bhh_r, ghz = bhh_z, ghn = bhh_n;
        #pragma unroll
        for (int i = 0; i < 8; ++i) {
            ghr = fmaf(h_full[i], whh_r[i], ghr);
            ghz = fmaf(h_full[i], whh_z[i], ghz);
            ghn = fmaf(h_full[i], whh_n[i], ghn);
        }
        const float r_ = sigmoidf_(fmaf(wih_r, cur, bih_r) + ghr);
        const float zg = sigmoidf_(fmaf(wih_z, cur, bih_z) + ghz);
        const float nn = tanhf_(fmaf(wih_n, cur, bih_n) + r_ * ghn);
        const float hn = (1.0f - zg) * nn + zg * h_own;
        h_own = hn;
        #pragma unroll
        for (int i = 0; i < 8; ++i) h_full[i] = __shfl(hn, i, 8);
        float p = opb;
        #pragma unroll
        for (int i = 0; i < 8; ++i) p = fmaf(h_full[i], opw[i], p);
        po_a = (s == j) ? p : po_a;
        po_b = (s == 8 + j) ? p : po_b;
        cur = p;
    }

    const float dk = __expf(log_decay[0]);
    float* orow = out + (size_t)row * 12;
    orow[j] = gate_a * po_a + (1.0f - gate_a) * last * __expf(-dk * (float)(j + 1));
    if (j < 4)
        orow[8 + j] = gate_b * po_b + (1.0f - gate_b) * last * __expf(-dk * (float)(j + 9));

    if (row == 0 && j == 0)
        out[(size_t)cROWS * 12] = __expf(log_reg[0]) * (1.0f / (float)cN);
}

extern "C" void kernel_launch(void* const* d_in, const int* in_sizes, int n_in,
                              void* d_out, int out_size, void* d_ws, size_t ws_size,
                              hipStream_t stream)
{
    const float* x      = (const float*)d_in[0];
    const float* dw_w   = (const float*)d_in[1];
    const float* dw_b   = (const float*)d_in[2];
    const float* bn1_g  = (const float*)d_in[3];
    const float* bn1_b  = (const float*)d_in[4];
    const float* bn1_m  = (const float*)d_in[5];
    const float* bn1_v  = (const float*)d_in[6];
    const float* pw_w   = (const float*)d_in[7];
    const float* pw_b   = (const float*)d_in[8];
    const float* bn2_g  = (const float*)d_in[9];
    const float* bn2_b  = (const float*)d_in[10];
    const float* bn2_m  = (const float*)d_in[11];
    const float* bn2_v  = (const float*)d_in[12];
    const float* fp_w   = (const float*)d_in[13];
    const float* fp_b   = (const float*)d_in[14];
    const float* lo_w   = (const float*)d_in[15];
    const float* lo_b   = (const float*)d_in[16];
    const float* hi_w   = (const float*)d_in[17];
    const float* hi_b   = (const float*)d_in[18];
    const float* olo_w  = (const float*)d_in[19];
    const float* olo_b  = (const float*)d_in[20];
    const float* ohi_w  = (const float*)d_in[21];
    const float* ohi_b  = (const float*)d_in[22];
    // d_in[23]=u, d_in[24]=v dead (softmax row-sums == 1 -> mean|attn| == 1/N)
    const float* log_reg = (const float*)d_in[25];
    const float* hp_w   = (const float*)d_in[26];
    const float* hp_b   = (const float*)d_in[27];
    const float* gru_wih = (const float*)d_in[28];
    const float* gru_whh = (const float*)d_in[29];
    const float* gru_bih = (const float*)d_in[30];
    const float* gru_bhh = (const float*)d_in[31];
    const float* op_w   = (const float*)d_in[32];
    const float* op_b   = (const float*)d_in[33];
    const float* log_decay = (const float*)d_in[34];
    const float* rg1_w  = (const float*)d_in[35];
    const float* rg1_b  = (const float*)d_in[36];
    const float* rg2_w  = (const float*)d_in[37];
    const float* rg2_b  = (const float*)d_in[38];

    float* ws = (float*)d_ws;
    unsigned short* wbt = (unsigned short*)ws;     // 32768 bf16 = 16384 float slots
    float* Wq     = ws + 16384;                    // 3072
    float* bq     = Wq + 3072;                     // 128 (96 used)
    float* qe     = bq + 128;                      // 409600 (z pre-folded)
    float* feat_c = qe + 409600;                   // 409600
    float* pkv    = feat_c + 409600;               // 204800 [800][256]

    k0_prep<<<128, 256, 0, stream>>>(fp_w, lo_w, lo_b, hi_w, hi_b,
                                     wbt, Wq, bq);
    kFQ<<<800, 256, 0, stream>>>(x, dw_w, dw_b, bn1_g, bn1_b, bn1_m, bn1_v,
                                 pw_w, pw_b, bn2_g, bn2_b, bn2_m, bn2_v,
                                 wbt, fp_b, Wq, bq,
                                 feat_c, qe, pkv);
    kB<<<400, 256, 0, stream>>>(x, feat_c, qe, pkv,
                                olo_w, olo_b, ohi_w, ohi_b,
                                hp_w, hp_b, gru_wih, gru_whh, gru_bih, gru_bhh,
                                op_w, op_b, log_decay,
                                rg1_w, rg1_b, rg2_w, rg2_b, log_reg,
                                (float*)d_out);
}